// Round 1
// baseline (520.084 us; speedup 1.0000x reference)
//
#include <hip/hip_runtime.h>
#include <hip/hip_bf16.h>

// Problem constants
#define DL 1024
#define DS 768
#define RK 64
#define GM 16384   // BATCH*SEQ
#define GN 3072    // 3*DL
#define GK 1024    // DL

// GEMM tile
#define BM 128
#define BN 128
#define BK 64

typedef __attribute__((ext_vector_type(8))) short bf16x8;
typedef __attribute__((ext_vector_type(4))) float f32x4;

__device__ __forceinline__ unsigned short f2bf(float f) {
    union { float f; unsigned int u; } v; v.f = f;
    unsigned int r = v.u + 0x7fffu + ((v.u >> 16) & 1u);  // RNE
    return (unsigned short)(r >> 16);
}

// ---------------------------------------------------------------- x -> bf16
__global__ void cvt_kernel(const float* __restrict__ x, unsigned short* __restrict__ xb, int n4) {
    int i = blockIdx.x * 256 + threadIdx.x;
    if (i < n4) {
        float4 v = ((const float4*)x)[i];
        ushort4 o;
        o.x = f2bf(v.x); o.y = f2bf(v.y); o.z = f2bf(v.z); o.w = f2bf(v.w);
        ((ushort4*)xb)[i] = o;
    }
}

// ------------------------------------------- T1[k][r][t] = sum_s B[k][r][s] * Ws[k][s][t]
// grid (DS/256=3, RK/8=8, 3), block 256
__global__ void t1_kernel(const float* __restrict__ W, const float* __restrict__ B,
                          float* __restrict__ T1) {
    int t  = blockIdx.x * 256 + threadIdx.x;
    int r0 = blockIdx.y * 8;
    int k  = blockIdx.z;
    const float* Wk = W + (size_t)k * DS * DS;
    const float* Bk = B + (size_t)k * RK * DS;
    float acc[8];
#pragma unroll
    for (int j = 0; j < 8; ++j) acc[j] = 0.f;
    for (int s = 0; s < DS; ++s) {
        float ws = Wk[(size_t)s * DS + t];
#pragma unroll
        for (int j = 0; j < 8; ++j) acc[j] += Bk[(size_t)(r0 + j) * DS + s] * ws;
    }
#pragma unroll
    for (int j = 0; j < 8; ++j)
        T1[((size_t)k * RK + (r0 + j)) * DS + t] = acc[j];
}

// ------------------------------------------- M[k][r][q] = sum_t T1[k][r][t] * B[k][q][t]
// one wave per output; grid 3*64*64/4 = 3072 blocks of 256
__global__ void m_kernel(const float* __restrict__ T1, const float* __restrict__ B,
                         float* __restrict__ Mm) {
    int w = blockIdx.x * 4 + (threadIdx.x >> 6);
    int lane = threadIdx.x & 63;
    int k = w / (RK * RK);
    int rem = w % (RK * RK);
    int r = rem / RK, q = rem % RK;
    const float* t1 = T1 + ((size_t)k * RK + r) * DS;
    const float* bq = B  + ((size_t)k * RK + q) * DS;
    float acc = 0.f;
    for (int t = lane; t < DS; t += 64) acc += t1[t] * bq[t];
#pragma unroll
    for (int off = 32; off > 0; off >>= 1) acc += __shfl_xor(acc, off, 64);
    if (lane == 0) Mm[w] = acc;
}

// ------------------------------------------- U[k][e][q] = sum_r A[k][e][r] * M[k][r][q]
// block 256 = 4 e x 64 q; grid 3*1024/4 = 768
__global__ void u_kernel(const float* __restrict__ A, const float* __restrict__ Mm,
                         float* __restrict__ U) {
    int q  = threadIdx.x & 63;
    int el = threadIdx.x >> 6;
    int k  = blockIdx.x / 256;
    int e  = (blockIdx.x % 256) * 4 + el;
    const float* Ae = A  + ((size_t)k * DL + e) * RK;
    const float* Mk = Mm + (size_t)k * RK * RK;
    float acc = 0.f;
#pragma unroll
    for (int r = 0; r < RK; ++r) acc += Ae[r] * Mk[r * RK + q];
    U[((size_t)k * DL + e) * RK + q] = acc;
}

// ------------------------------------------- At[k][q][d] = A[k][d][q]
__global__ void at_kernel(const float* __restrict__ A, float* __restrict__ At) {
    int i = blockIdx.x * 256 + threadIdx.x;     // i = (k*RK + q)*DL + d
    int d = i % DL;
    int kq = i / DL;
    int q = kq % RK, k = kq / RK;
    At[i] = A[((size_t)k * DL + d) * RK + q];
}

// ------------------------------------------- Wc[k*DL+e][d] = bf16( sum_q U[k][e][q]*At[k][q][d] )
// block 256 d; 8 e per thread; grid 3 * 128 * 4 = 1536
__global__ void wcat_kernel(const float* __restrict__ U, const float* __restrict__ At,
                            unsigned short* __restrict__ Wc) {
    int d  = (blockIdx.x % 4) * 256 + threadIdx.x;
    int e0 = ((blockIdx.x / 4) % 128) * 8;
    int k  = blockIdx.x / 512;
    const float* Uk  = U  + (size_t)k * DL * RK;
    const float* Atk = At + (size_t)k * RK * DL;
    float acc[8];
#pragma unroll
    for (int j = 0; j < 8; ++j) acc[j] = 0.f;
    for (int q = 0; q < RK; ++q) {
        float a = Atk[(size_t)q * DL + d];
#pragma unroll
        for (int j = 0; j < 8; ++j) acc[j] += Uk[(size_t)(e0 + j) * RK + q] * a;
    }
#pragma unroll
    for (int j = 0; j < 8; ++j)
        Wc[((size_t)k * DL + (e0 + j)) * GK + d] = f2bf(acc[j]);
}

// ------------------------------------------- main GEMM: C[M,N] = Xb[M,K] * Wc[N,K]^T
__global__ __launch_bounds__(256) void gemm_kernel(const unsigned short* __restrict__ Ag,
                                                   const unsigned short* __restrict__ Bg,
                                                   float* __restrict__ C) {
    __shared__ unsigned short As[BM * BK];
    __shared__ unsigned short Bs[BN * BK];

    const int tid  = threadIdx.x;
    const int wave = tid >> 6;
    const int lane = tid & 63;
    const int bm0 = blockIdx.y * BM;
    const int bn0 = blockIdx.x * BN;
    const int wr = wave >> 1;        // 0..1 : 64-row band
    const int wc = wave & 1;         // 0..1 : 64-col band

    const int srow = lane >> 3;          // 0..7 row within 8-row staging group
    const int scol = (lane & 7) * 8;     // bf16 offset within BK

    f32x4 acc[4][4];
#pragma unroll
    for (int i = 0; i < 4; ++i)
#pragma unroll
        for (int j = 0; j < 4; ++j) {
            f32x4 z = {0.f, 0.f, 0.f, 0.f};
            acc[i][j] = z;
        }

    const unsigned short* Abase = Ag + (size_t)bm0 * GK;
    const unsigned short* Bbase = Bg + (size_t)bn0 * GK;

    for (int kt = 0; kt < GK / BK; ++kt) {
        __syncthreads();  // previous compute done before overwriting LDS
        const int k0 = kt * BK;
#pragma unroll
        for (int i = 0; i < 4; ++i) {
            const int grp = wave * 4 + i;          // 0..15, 8-row group
            const int row = grp * 8 + srow;
            __builtin_amdgcn_global_load_lds(
                (const __attribute__((address_space(1))) void*)(Abase + (size_t)row * GK + k0 + scol),
                (__attribute__((address_space(3))) void*)(As + grp * 512),
                16, 0, 0);
            __builtin_amdgcn_global_load_lds(
                (const __attribute__((address_space(1))) void*)(Bbase + (size_t)row * GK + k0 + scol),
                (__attribute__((address_space(3))) void*)(Bs + grp * 512),
                16, 0, 0);
        }
        __syncthreads();  // drains vmcnt(0): staged tile visible to all waves

#pragma unroll
        for (int ks = 0; ks < 2; ++ks) {
            bf16x8 af[4], bfr[4];
            const int kk = ks * 32 + (lane >> 4) * 8;
            const int rr = lane & 15;
#pragma unroll
            for (int i = 0; i < 4; ++i) {
                af[i]  = *(const bf16x8*)(As + (wr * 64 + i * 16 + rr) * BK + kk);
                bfr[i] = *(const bf16x8*)(Bs + (wc * 64 + i * 16 + rr) * BK + kk);
            }
#pragma unroll
            for (int i = 0; i < 4; ++i)
#pragma unroll
                for (int j = 0; j < 4; ++j)
                    acc[i][j] = __builtin_amdgcn_mfma_f32_16x16x32_bf16(
                        af[i], bfr[j], acc[i][j], 0, 0, 0);
        }
    }

    // epilogue: D layout col=lane&15, row=(lane>>4)*4+reg
    const int cn = lane & 15;
    const int rg = (lane >> 4) * 4;
#pragma unroll
    for (int i = 0; i < 4; ++i) {
#pragma unroll
        for (int j = 0; j < 4; ++j) {
            const int m0 = bm0 + wr * 64 + i * 16 + rg;
            const int n  = bn0 + wc * 64 + j * 16 + cn;
#pragma unroll
            for (int r = 0; r < 4; ++r)
                C[(size_t)(m0 + r) * GN + n] = acc[i][j][r];
        }
    }
}

extern "C" void kernel_launch(void* const* d_in, const int* in_sizes, int n_in,
                              void* d_out, int out_size, void* d_ws, size_t ws_size,
                              hipStream_t stream) {
    const float* x   = (const float*)d_in[0];
    const float* Wsm = (const float*)d_in[1];
    const float* A   = (const float*)d_in[2];
    const float* B   = (const float*)d_in[3];
    float* out = (float*)d_out;
    char* ws = (char*)d_ws;

    unsigned short* xb = (unsigned short*)(ws);                       // 33,554,432 B
    unsigned short* Wc = (unsigned short*)(ws + 33554432);            //  6,291,456 B
    float* T1          = (float*)(ws + 39845888);                     //    589,824 B
    float* Mm          = (float*)(ws + 40435712);                     //     49,152 B
    float* U           = (float*)(ws + 40484864);                     //    786,432 B
    float* At          = (float*)(ws + 41271296);                     //    786,432 B

    cvt_kernel<<<GM * GK / 4 / 256, 256, 0, stream>>>(x, xb, GM * GK / 4);
    t1_kernel<<<dim3(3, 8, 3), 256, 0, stream>>>(Wsm, B, T1);
    m_kernel<<<3 * RK * RK / 4, 256, 0, stream>>>(T1, B, Mm);
    u_kernel<<<3 * DL / 4, 256, 0, stream>>>(A, Mm, U);
    at_kernel<<<3 * RK * DL / 256, 256, 0, stream>>>(A, At);
    wcat_kernel<<<1536, 256, 0, stream>>>(U, At, Wc);
    gemm_kernel<<<dim3(GN / BN, GM / BM), 256, 0, stream>>>(xb, Wc, out);
}

// Round 2
// 430.195 us; speedup vs baseline: 1.2090x; 1.2090x over previous
//
#include <hip/hip_runtime.h>
#include <hip/hip_bf16.h>

// Problem constants
#define DL 1024
#define DS 768
#define RK 64
#define GM 16384   // BATCH*SEQ
#define GN 3072    // 3*DL
#define GK 1024    // DL

// GEMM tile: 256x128, BK=64, 512 threads (8 waves, each 64x64)
#define BM 256
#define BN 128
#define BK 64

typedef __attribute__((ext_vector_type(8))) short bf16x8;
typedef __attribute__((ext_vector_type(4))) float f32x4;

__device__ __forceinline__ unsigned short f2bf(float f) {
    union { float f; unsigned int u; } v; v.f = f;
    unsigned int r = v.u + 0x7fffu + ((v.u >> 16) & 1u);  // RNE
    return (unsigned short)(r >> 16);
}

// ---------------------------------------------------------------- x -> bf16
__global__ void cvt_kernel(const float* __restrict__ x, unsigned short* __restrict__ xb, int n4) {
    int i = blockIdx.x * 256 + threadIdx.x;
    if (i < n4) {
        float4 v = ((const float4*)x)[i];
        ushort4 o;
        o.x = f2bf(v.x); o.y = f2bf(v.y); o.z = f2bf(v.z); o.w = f2bf(v.w);
        ((ushort4*)xb)[i] = o;
    }
}

// ------------------------------------------- T1[k][r][t] = sum_s B[k][r][s] * Ws[k][s][t]
// grid (DS/256=3, RK/8=8, 3), block 256. B-rows staged in LDS (kills the
// 8-deep dependent scalar-load chain of the previous version).
__global__ void t1_kernel(const float* __restrict__ W, const float* __restrict__ B,
                          float* __restrict__ T1) {
    __shared__ float Bsh[8 * DS];          // 24 KB
    int t  = blockIdx.x * 256 + threadIdx.x;
    int r0 = blockIdx.y * 8;
    int k  = blockIdx.z;
    const float* Wk = W + (size_t)k * DS * DS;
    const float* Bk = B + ((size_t)k * RK + r0) * DS;
    for (int i = threadIdx.x; i < 8 * DS; i += 256) Bsh[i] = Bk[i];
    __syncthreads();
    float acc[8];
#pragma unroll
    for (int j = 0; j < 8; ++j) acc[j] = 0.f;
    for (int s = 0; s < DS; ++s) {
        float ws = Wk[(size_t)s * DS + t];
#pragma unroll
        for (int j = 0; j < 8; ++j) acc[j] += Bsh[j * DS + s] * ws;
    }
#pragma unroll
    for (int j = 0; j < 8; ++j)
        T1[((size_t)k * RK + (r0 + j)) * DS + t] = acc[j];
}

// ------------------------------------------- M[k][r][q] = sum_t T1[k][r][t] * B[k][q][t]
__global__ void m_kernel(const float* __restrict__ T1, const float* __restrict__ B,
                         float* __restrict__ Mm) {
    int w = blockIdx.x * 4 + (threadIdx.x >> 6);
    int lane = threadIdx.x & 63;
    int k = w / (RK * RK);
    int rem = w % (RK * RK);
    int r = rem / RK, q = rem % RK;
    const float* t1 = T1 + ((size_t)k * RK + r) * DS;
    const float* bq = B  + ((size_t)k * RK + q) * DS;
    float acc = 0.f;
    for (int t = lane; t < DS; t += 64) acc += t1[t] * bq[t];
#pragma unroll
    for (int off = 32; off > 0; off >>= 1) acc += __shfl_xor(acc, off, 64);
    if (lane == 0) Mm[w] = acc;
}

// ------------------------------------------- U[k][e][q] = sum_r A[k][e][r] * M[k][r][q]
__global__ void u_kernel(const float* __restrict__ A, const float* __restrict__ Mm,
                         float* __restrict__ U) {
    int q  = threadIdx.x & 63;
    int el = threadIdx.x >> 6;
    int k  = blockIdx.x / 256;
    int e  = (blockIdx.x % 256) * 4 + el;
    const float* Ae = A  + ((size_t)k * DL + e) * RK;
    const float* Mk = Mm + (size_t)k * RK * RK;
    float acc = 0.f;
#pragma unroll
    for (int r = 0; r < RK; ++r) acc += Ae[r] * Mk[r * RK + q];
    U[((size_t)k * DL + e) * RK + q] = acc;
}

// ------------------------------------------- At[k][q][d] = A[k][d][q]
__global__ void at_kernel(const float* __restrict__ A, float* __restrict__ At) {
    int i = blockIdx.x * 256 + threadIdx.x;     // i = (k*RK + q)*DL + d
    int d = i % DL;
    int kq = i / DL;
    int q = kq % RK, k = kq / RK;
    At[i] = A[((size_t)k * DL + d) * RK + q];
}

// ------------------------------------------- Wc[k*DL+e][d] = bf16( sum_q U[k][e][q]*At[k][q][d] )
// U-rows staged in LDS (same dependent-scalar-load fix as t1).
__global__ void wcat_kernel(const float* __restrict__ U, const float* __restrict__ At,
                            unsigned short* __restrict__ Wc) {
    __shared__ float Ush[8 * RK];          // 2 KB
    int d  = (blockIdx.x & 3) * 256 + threadIdx.x;
    int e0 = ((blockIdx.x >> 2) & 127) * 8;
    int k  = blockIdx.x >> 9;
    const float* Uk  = U  + ((size_t)k * DL + e0) * RK;
    const float* Atk = At + (size_t)k * RK * DL;
    for (int i = threadIdx.x; i < 8 * RK; i += 256) Ush[i] = Uk[i];
    __syncthreads();
    float acc[8];
#pragma unroll
    for (int j = 0; j < 8; ++j) acc[j] = 0.f;
    for (int q = 0; q < RK; ++q) {
        float a = Atk[(size_t)q * DL + d];
#pragma unroll
        for (int j = 0; j < 8; ++j) acc[j] += Ush[j * RK + q] * a;
    }
#pragma unroll
    for (int j = 0; j < 8; ++j)
        Wc[((size_t)k * DL + (e0 + j)) * GK + d] = f2bf(acc[j]);
}

// ------------------------------------------- main GEMM: C[M,N] = Xb[M,K] * Wc[N,K]^T
// 256x128 tile, 8 waves (4 wave-rows x 2 wave-cols, each 64x64).
// XOR-swizzled staging: global chunk c of row r lands at LDS chunk c^(r&7),
// so fragment reads (16 consecutive rows, same k-chunk) hit 8 distinct
// bank-quads -> 2-way max (free) instead of 16-way.
__global__ __launch_bounds__(512, 4) void gemm_kernel(const unsigned short* __restrict__ Ag,
                                                      const unsigned short* __restrict__ Bg,
                                                      float* __restrict__ C) {
    __shared__ unsigned short As[BM * BK];   // 32 KB
    __shared__ unsigned short Bs[BN * BK];   // 16 KB

    const int tid  = threadIdx.x;
    const int wave = tid >> 6;
    const int lane = tid & 63;
    const int bm0 = blockIdx.y * BM;
    const int bn0 = blockIdx.x * BN;
    const int wr = wave >> 1;        // 0..3 : 64-row band
    const int wc = wave & 1;         // 0..1 : 64-col band

    const int srow = lane >> 3;              // 0..7 row within 8-row staging group
    const int gcol = ((lane & 7) ^ srow) * 8; // swizzled source chunk (bf16 offset)

    f32x4 acc[4][4];
#pragma unroll
    for (int i = 0; i < 4; ++i)
#pragma unroll
        for (int j = 0; j < 4; ++j) {
            f32x4 z = {0.f, 0.f, 0.f, 0.f};
            acc[i][j] = z;
        }

    const unsigned short* Abase = Ag + (size_t)bm0 * GK;
    const unsigned short* Bbase = Bg + (size_t)bn0 * GK;

    for (int kt = 0; kt < GK / BK; ++kt) {
        __syncthreads();  // previous compute done before overwriting LDS
        const int k0 = kt * BK;
#pragma unroll
        for (int i = 0; i < 4; ++i) {          // A: 32 groups of 8 rows
            const int grp = wave * 4 + i;
            const int row = grp * 8 + srow;
            __builtin_amdgcn_global_load_lds(
                (const __attribute__((address_space(1))) void*)(Abase + (size_t)row * GK + k0 + gcol),
                (__attribute__((address_space(3))) void*)(As + grp * 512),
                16, 0, 0);
        }
#pragma unroll
        for (int i = 0; i < 2; ++i) {          // B: 16 groups of 8 rows
            const int grp = wave * 2 + i;
            const int row = grp * 8 + srow;
            __builtin_amdgcn_global_load_lds(
                (const __attribute__((address_space(1))) void*)(Bbase + (size_t)row * GK + k0 + gcol),
                (__attribute__((address_space(3))) void*)(Bs + grp * 512),
                16, 0, 0);
        }
        __syncthreads();  // drains vmcnt(0): staged tile visible to all waves

        const int rr = lane & 15;
        const int sw = rr & 7;
        const int cq = lane >> 4;            // 0..3
#pragma unroll
        for (int ks = 0; ks < 2; ++ks) {
            const int ca = ((ks * 4 + cq) ^ sw) * 8;   // swizzled chunk offset (shorts)
            bf16x8 af[4], bfr[4];
#pragma unroll
            for (int i = 0; i < 4; ++i) {
                af[i]  = *(const bf16x8*)(As + (wr * 64 + i * 16 + rr) * BK + ca);
                bfr[i] = *(const bf16x8*)(Bs + (wc * 64 + i * 16 + rr) * BK + ca);
            }
#pragma unroll
            for (int i = 0; i < 4; ++i)
#pragma unroll
                for (int j = 0; j < 4; ++j)
                    acc[i][j] = __builtin_amdgcn_mfma_f32_16x16x32_bf16(
                        af[i], bfr[j], acc[i][j], 0, 0, 0);
        }
    }

    // epilogue: D layout col=lane&15, row=(lane>>4)*4+reg
    const int cn = lane & 15;
    const int rg = (lane >> 4) * 4;
#pragma unroll
    for (int i = 0; i < 4; ++i) {
#pragma unroll
        for (int j = 0; j < 4; ++j) {
            const int m0 = bm0 + wr * 64 + i * 16 + rg;
            const int n  = bn0 + wc * 64 + j * 16 + cn;
#pragma unroll
            for (int r = 0; r < 4; ++r)
                C[(size_t)(m0 + r) * GN + n] = acc[i][j][r];
        }
    }
}

extern "C" void kernel_launch(void* const* d_in, const int* in_sizes, int n_in,
                              void* d_out, int out_size, void* d_ws, size_t ws_size,
                              hipStream_t stream) {
    const float* x   = (const float*)d_in[0];
    const float* Wsm = (const float*)d_in[1];
    const float* A   = (const float*)d_in[2];
    const float* B   = (const float*)d_in[3];
    float* out = (float*)d_out;
    char* ws = (char*)d_ws;

    unsigned short* xb = (unsigned short*)(ws);                       // 33,554,432 B
    unsigned short* Wc = (unsigned short*)(ws + 33554432);            //  6,291,456 B
    float* T1          = (float*)(ws + 39845888);                     //    589,824 B
    float* Mm          = (float*)(ws + 40435712);                     //     49,152 B
    float* U           = (float*)(ws + 40484864);                     //    786,432 B
    float* At          = (float*)(ws + 41271296);                     //    786,432 B

    cvt_kernel<<<GM * GK / 4 / 256, 256, 0, stream>>>(x, xb, GM * GK / 4);
    t1_kernel<<<dim3(3, 8, 3), 256, 0, stream>>>(Wsm, B, T1);
    m_kernel<<<3 * RK * RK / 4, 256, 0, stream>>>(T1, B, Mm);
    u_kernel<<<3 * DL / 4, 256, 0, stream>>>(A, Mm, U);
    at_kernel<<<3 * RK * DL / 256, 256, 0, stream>>>(A, At);
    wcat_kernel<<<1536, 256, 0, stream>>>(U, At, Wc);
    gemm_kernel<<<dim3(GN / BN, GM / BM), 512, 0, stream>>>(xb, Wc, out);
}